// Round 8
// baseline (271.934 us; speedup 1.0000x reference)
//
#include <hip/hip_runtime.h>

// Problem constants (fixed by setup_inputs)
#define BQ   4
#define CQ   2
#define EQ   256
#define LQ   16000
#define WQ   40
#define STEP 20
#define TQ   ((LQ - 1) * STEP + WQ)   // 320020
#define FBP  252                      // frame-base pitch (FB = 252*bx, 16B-aligned f0)
#define NBX  64                       // 252*63 + 255 = 16131 >= 15999
#define SPAN (255 * STEP + WQ)        // 5140 floats per accumulation copy
#define OWNP (FBP * STEP)             // 5040 owned-output pitch
#define OWNE (OWNP + STEP)            // 5060 owned-range end (LDS index)
#define NH   4                        // e-quarters (one per wave)
#define EH   (EQ / NH)                // 64 e's per wave
#define FPT  4                        // consecutive frames per thread (float4 loads)

// Pre-kernel: transpose basis [W][E] -> wsT [E][W] fp32.
__global__ void transpose_basis_kernel(const float* __restrict__ basis,
                                       float* __restrict__ wsT) {
    int i = blockIdx.x * 256 + threadIdx.x;
    if (i < EQ * WQ) {
        int e = i / WQ;
        int w = i - e * WQ;
        wsT[i] = basis[w * EQ + e];
    }
}

// One block: 256 threads = 4 waves; wave wv owns e-quarter [wv*64, wv*64+64).
// Thread (wv, lane) owns 4 CONSECUTIVE frames g = 4*lane..4*lane+3,
// f = 252*bx + g, so each (e)-step loads mix/mask as ONE float4 (16 B/lane,
// 1 KB/wave-load). This is the R2-R7 fix: scalar dword gathers at 64 KB
// stride pinned a few L2 channels and kept only ~1 load in flight; float4
// spreads channels and quadruples in-flight bytes. Depth-2 rotating prefetch.
// Basis rows broadcast from LDS (10 ds_read_b128 per 160 FMAs).
// Epilogue: zero 2 LDS copies (wave-pair each), 4 parity phases of float4
// read-modify-write (intra-thread overlaps are same-lane ordered; ranges
// across threads within a phase are disjoint), then one coalesced store of
// the owned span.
__global__ __launch_bounds__(256) void decoder_kernel(
    const float* __restrict__ mix,    // [B,E,L]
    const float* __restrict__ mask,   // [B,C,E,L]
    const float* __restrict__ wsT,    // [E,W] transposed basis
    float* __restrict__ out)          // [B,C,T]
{
    __shared__ __align__(16) float smem[2 * SPAN];  // 41.1 KB; basisT aliases front

    const int tid  = threadIdx.x;
    const int lane = tid & 63;
    const int wv   = tid >> 6;
    const int bx   = blockIdx.x;
    const int b    = blockIdx.y;
    const int c    = blockIdx.z;

    // Stage basisT into LDS.
    float* basisT = smem;
    for (int i = tid; i < EQ * WQ; i += 256) basisT[i] = wsT[i];
    __syncthreads();

    // 4 consecutive frames: f0 = 252*bx + 4*lane (16B-aligned address).
    const int f0  = FBP * bx + FPT * lane;
    const int f0c = min(f0, LQ - 4);          // in-bounds float4 address
    float4 valid;
    valid.x = (f0 + 0 < LQ) ? 1.0f : 0.0f;
    valid.y = (f0 + 1 < LQ) ? 1.0f : 0.0f;
    valid.z = (f0 + 2 < LQ) ? 1.0f : 0.0f;
    valid.w = (f0 + 3 < LQ) ? 1.0f : 0.0f;

    float4 acc[FPT][WQ / 4];
#pragma unroll
    for (int j = 0; j < FPT; ++j)
#pragma unroll
        for (int t = 0; t < WQ / 4; ++t) acc[j][t] = make_float4(0.f, 0.f, 0.f, 0.f);

    const float* mp = mix  + ((size_t)b * EQ + wv * EH) * LQ + f0c;
    const float* kp = mask + (((size_t)(b * CQ + c)) * EQ + wv * EH) * LQ + f0c;

    // Depth-2 rotating prefetch (one float4 per stream per stage).
    float4 mS[2], kS[2];
    mS[0] = *(const float4*)(mp);
    kS[0] = *(const float4*)(kp);
    mS[1] = *(const float4*)(mp + LQ);
    kS[1] = *(const float4*)(kp + LQ);

    for (int eo = 0; eo < EH; eo += 2) {
#pragma unroll
        for (int st = 0; st < 2; ++st) {
            const int e = eo + st;
            float4 s4;
            s4.x = mS[st].x * kS[st].x * valid.x;
            s4.y = mS[st].y * kS[st].y * valid.y;
            s4.z = mS[st].z * kS[st].z * valid.z;
            s4.w = mS[st].w * kS[st].w * valid.w;
            const int en = min(e + 2, EH - 1);   // branch-free refill clamp
            mS[st] = *(const float4*)(mp + (size_t)en * LQ);
            kS[st] = *(const float4*)(kp + (size_t)en * LQ);
            const float4* bt = (const float4*)&basisT[(wv * EH + e) * WQ];
#pragma unroll
            for (int t = 0; t < WQ / 4; ++t) {
                float4 bv = bt[t];   // wave-uniform broadcast
                acc[0][t].x = fmaf(s4.x, bv.x, acc[0][t].x);
                acc[0][t].y = fmaf(s4.x, bv.y, acc[0][t].y);
                acc[0][t].z = fmaf(s4.x, bv.z, acc[0][t].z);
                acc[0][t].w = fmaf(s4.x, bv.w, acc[0][t].w);
                acc[1][t].x = fmaf(s4.y, bv.x, acc[1][t].x);
                acc[1][t].y = fmaf(s4.y, bv.y, acc[1][t].y);
                acc[1][t].z = fmaf(s4.y, bv.z, acc[1][t].z);
                acc[1][t].w = fmaf(s4.y, bv.w, acc[1][t].w);
                acc[2][t].x = fmaf(s4.z, bv.x, acc[2][t].x);
                acc[2][t].y = fmaf(s4.z, bv.y, acc[2][t].y);
                acc[2][t].z = fmaf(s4.z, bv.z, acc[2][t].z);
                acc[2][t].w = fmaf(s4.z, bv.w, acc[2][t].w);
                acc[3][t].x = fmaf(s4.w, bv.x, acc[3][t].x);
                acc[3][t].y = fmaf(s4.w, bv.y, acc[3][t].y);
                acc[3][t].z = fmaf(s4.w, bv.z, acc[3][t].z);
                acc[3][t].w = fmaf(s4.w, bv.w, acc[3][t].w);
            }
        }
    }
    __syncthreads();   // basisT dead; smem becomes 2 accumulation copies

    // Zero both accumulation copies.
    for (int i = tid; i < 2 * SPAN; i += 256) smem[i] = 0.0f;
    __syncthreads();

    // Overlap-add: copy cp = wv>>1; 4 phases over (wave-pair member, lane
    // parity). Thread covers [80*lane, 80*lane+100): within a phase, active
    // lanes differ by >=2 -> ranges disjoint (160 >= 100). Same-thread jj
    // overlaps are ordered LDS ops. All float4 ops 16B-aligned (80*g bytes).
    float* outC = smem + (wv >> 1) * SPAN;
    const int hp = wv & 1;
    const int lp = lane & 1;
#pragma unroll
    for (int ph = 0; ph < 4; ++ph) {
        if (hp == (ph >> 1) && lp == (ph & 1)) {
#pragma unroll
            for (int j = 0; j < FPT; ++j) {
                float4* p = (float4*)(outC + (FPT * lane + j) * STEP);
#pragma unroll
                for (int t = 0; t < WQ / 4; ++t) {
                    float4 v = p[t];
                    v.x += acc[j][t].x; v.y += acc[j][t].y;
                    v.z += acc[j][t].z; v.w += acc[j][t].w;
                    p[t] = v;
                }
            }
        }
        __syncthreads();
    }

    // Store owned span: t = 5040*bx + i, i in [start, 5060); block 0 also
    // owns [0,20) (frame -1 doesn't exist there).
    const int start = (bx == 0) ? 0 : STEP;
    const size_t ob = ((size_t)(b * CQ + c)) * TQ + (size_t)OWNP * bx;
    for (int i = tid; i < OWNE; i += 256) {
        if (i >= start) {
            const long t = (long)OWNP * bx + i;
            if (t < (long)TQ) {
                out[ob + i] = smem[i] + smem[SPAN + i];
            }
        }
    }
}

extern "C" void kernel_launch(void* const* d_in, const int* in_sizes, int n_in,
                              void* d_out, int out_size, void* d_ws, size_t ws_size,
                              hipStream_t stream) {
    const float* mix   = (const float*)d_in[0];
    const float* mask  = (const float*)d_in[1];
    const float* basis = (const float*)d_in[2];
    float* out = (float*)d_out;
    float* wsT = (float*)d_ws;   // needs EQ*WQ*4 = 40960 bytes

    transpose_basis_kernel<<<dim3((EQ * WQ + 255) / 256), 256, 0, stream>>>(basis, wsT);

    dim3 grid(NBX, BQ, CQ);
    decoder_kernel<<<grid, 256, 0, stream>>>(mix, mask, wsT, out);
}

// Round 9
// 247.916 us; speedup vs baseline: 1.0969x; 1.0969x over previous
//
#include <hip/hip_runtime.h>

// Problem constants (fixed by setup_inputs)
#define BQ   4
#define CQ   2
#define EQ   256
#define LQ   16000
#define WQ   40
#define STEP 20
#define TQ   ((LQ - 1) * STEP + WQ)   // 320020
#define NBX  254                      // blocks per (b,c); 254*1260 = 320040 >= 320020
#define OWN  1260                     // owned output samples per block (63 frames * 20)
#define NKC  8                        // K-chunks of 32 e
#define NNT  3                        // N-tiles of 16 w (48 cols; w>=40 zero-padded)
#define FR   64                       // frames computed per block (4 waves x 16)
#define FSTR 52                       // frameBuf row stride (2-way-only bank aliasing)
#define NBF  (NKC * NNT * 4 * 64)     // 6144 packed-f16-pair uints of B-fragments

typedef _Float16 f16x8 __attribute__((ext_vector_type(8)));
typedef float    f32x4 __attribute__((ext_vector_type(4)));

// Pre-kernel: bake basis [W][E] fp32 into exact mfma_f32_16x16x32_f16
// B-fragment layout, f16 (RTN), zero-padded to 48 cols.
// Layout: wsF[((kc*3 + nt)*64 + lane)*4 + p] = pack(k=kc*32+quad*8+2p, 2p+1)
// where n = nt*16 + (lane&15), quad = lane>>4.  B[k][n] mapping: n=lane&15,
// k=quad*8+j (j = element index), pairs packed lo/hi.
__global__ void build_bfrag_kernel(const float* __restrict__ basis,
                                   unsigned* __restrict__ wsF) {
    int i = blockIdx.x * 256 + threadIdx.x;
    if (i >= NBF) return;
    int p    = i & 3;
    int lane = (i >> 2) & 63;
    int q    = i >> 8;          // kc*3 + nt
    int nt   = q % NNT;
    int kc   = q / NNT;
    int n = nt * 16 + (lane & 15);
    int k = kc * 32 + (lane >> 4) * 8 + 2 * p;
    float lo = (n < WQ) ? basis[n * EQ + k]     : 0.0f;   // basis is [W][E]
    float hi = (n < WQ) ? basis[n * EQ + k + 1] : 0.0f;
    union { _Float16 h[2]; unsigned u; } cv;
    cv.h[0] = (_Float16)lo;
    cv.h[1] = (_Float16)hi;
    wsF[i] = cv.u;
}

// One block: 256 threads = 4 waves; wave wv computes M-tile of 16 frames
// f = 63*bx - 1 + 16*wv + m (m = lane&15) over all 256 e via 8 MFMA K-chunks
// x 3 N-tiles. A-frag: lane holds s = mix*mask (f16) for (m, k=quad*8+j).
// B-frags come from LDS (1 ds_read_b128 each). D: col=lane&15=w-in-tile,
// row=quad*4+reg=frame-in-tile. Epilogue: D -> frameBuf[64][52], barrier,
// out[t] = frameBuf[f0-fb][w0] + frameBuf[f0-1-fb][w0+20] over the block's
// disjoint owned span t in [1260*bx, 1260*bx+1260). Out-of-range frames are
// zeroed via the valid multiplier, so edges need no special cases.
__global__ __launch_bounds__(256) void decoder_kernel(
    const float* __restrict__ mix,    // [B,E,L]
    const float* __restrict__ mask,   // [B,C,E,L]
    const unsigned* __restrict__ wsF, // baked B-fragments
    float* __restrict__ out)          // [B,C,T]
{
    __shared__ unsigned bfragS[NBF];            // 24 KB
    __shared__ float frameBuf[FR * FSTR];       // 13.3 KB

    const int tid  = threadIdx.x;
    const int lane = tid & 63;
    const int wv   = tid >> 6;
    const int bx   = blockIdx.x;
    const int b    = blockIdx.y;
    const int c    = blockIdx.z;

    // Stage B-fragments into LDS (coalesced dwords).
    for (int i = tid; i < NBF; i += 256) bfragS[i] = wsF[i];
    __syncthreads();

    const int m    = lane & 15;       // frame-in-tile (A-operand M index)
    const int quad = lane >> 4;
    const int f    = 63 * bx - 1 + 16 * wv + m;
    const int fc   = min(max(f, 0), LQ - 1);
    const float vf = (f >= 0 && f < LQ) ? 1.0f : 0.0f;

    const float* mp = mix  + (size_t)b * EQ * LQ
                            + (size_t)(quad * 8) * LQ + fc;
    const float* kp = mask + ((size_t)(b * CQ + c)) * EQ * LQ
                            + (size_t)(quad * 8) * LQ + fc;

    f32x4 acc[NNT];
#pragma unroll
    for (int nt = 0; nt < NNT; ++nt) acc[nt] = (f32x4){0.f, 0.f, 0.f, 0.f};

#pragma unroll
    for (int kc = 0; kc < NKC; ++kc) {
        // A-fragment: s[j] for k = kc*32 + quad*8 + j. 16 independent dword
        // loads (16-consecutive-f x 4-e-row segments per instruction).
        float sv[8];
#pragma unroll
        for (int j = 0; j < 8; ++j) {
            float mv = mp[(size_t)(kc * 32 + j) * LQ];
            float kv = kp[(size_t)(kc * 32 + j) * LQ];
            sv[j] = mv * kv * vf;
        }
        f16x8 a;
#pragma unroll
        for (int j = 0; j < 8; ++j) a[j] = (_Float16)sv[j];   // RTN cvt

#pragma unroll
        for (int nt = 0; nt < NNT; ++nt) {
            union { uint4 u; f16x8 v; } bb;
            bb.u = ((const uint4*)bfragS)[(kc * NNT + nt) * 64 + lane];
            acc[nt] = __builtin_amdgcn_mfma_f32_16x16x32_f16(a, bb.v, acc[nt],
                                                             0, 0, 0);
        }
    }

    // Scatter D to frameBuf: frame-in-block = 16*wv + quad*4 + r, w = nt*16+m.
    // Stride 52 -> quads alias banks at most 2-way (free).
#pragma unroll
    for (int nt = 0; nt < NNT; ++nt)
#pragma unroll
        for (int r = 0; r < 4; ++r)
            frameBuf[(16 * wv + quad * 4 + r) * FSTR + nt * 16 + m] = acc[nt][r];
    __syncthreads();

    // Owned span: t = 1260*bx + i, i in [0,1260): f0 = 63*bx + i/20,
    // buffer row of f0 is i/20 + 1, of f0-1 is i/20.
    const size_t ob = ((size_t)(b * CQ + c)) * TQ + (size_t)OWN * bx;
    for (int i = tid; i < OWN; i += 256) {
        const long t = (long)OWN * bx + i;
        if (t < (long)TQ) {
            int q20 = i / 20;
            int r20 = i - q20 * 20;
            out[ob + i] = frameBuf[(q20 + 1) * FSTR + r20]
                        + frameBuf[q20 * FSTR + r20 + STEP];
        }
    }
}

extern "C" void kernel_launch(void* const* d_in, const int* in_sizes, int n_in,
                              void* d_out, int out_size, void* d_ws, size_t ws_size,
                              hipStream_t stream) {
    const float* mix   = (const float*)d_in[0];
    const float* mask  = (const float*)d_in[1];
    const float* basis = (const float*)d_in[2];
    float* out = (float*)d_out;
    unsigned* wsF = (unsigned*)d_ws;   // needs NBF*4 = 24576 bytes

    build_bfrag_kernel<<<dim3((NBF + 255) / 256), 256, 0, stream>>>(basis, wsF);

    dim3 grid(NBX, BQ, CQ);
    decoder_kernel<<<grid, 256, 0, stream>>>(mix, mask, wsF, out);
}